// Round 1
// baseline (583.631 us; speedup 1.0000x reference)
//
#include <hip/hip_runtime.h>
#include <math.h>

#define DD 128
#define HH 128
#define WW 128
#define NN (DD*HH*WW)
#define DJ 127

// ---------- block reduction helper ----------
__device__ __forceinline__ double wave_reduce(double v) {
    #pragma unroll
    for (int o = 32; o > 0; o >>= 1) v += __shfl_down(v, o);
    return v;
}

// All threads of the block must call this (no early returns).
__device__ __forceinline__ void block_atomic_add(double v, double* dst, int tid, int nthreads) {
    __shared__ double red[8];   // up to 512 threads = 8 waves
    v = wave_reduce(v);
    int wid = tid >> 6, lane = tid & 63;
    if (lane == 0) red[wid] = v;
    __syncthreads();
    if (wid == 0) {
        int nw = nthreads >> 6;
        double x = (lane < nw) ? red[lane] : 0.0;
        x = wave_reduce(x);
        if (lane == 0) atomicAdd(dst, x);
    }
}

// ---------- 1) LNCC ----------
#define TB 8
#define TH 12   // TB + 2*2 halo

__global__ __launch_bounds__(512) void lncc_kernel(const float* __restrict__ src,
                                                   const float* __restrict__ tgt,
                                                   double* __restrict__ ws) {
    __shared__ float sS[TH][TH][TH];
    __shared__ float sT[TH][TH][TH];
    const int bx = blockIdx.x * TB, by = blockIdx.y * TB, bz = blockIdx.z * TB;
    const int tid = threadIdx.z * 64 + threadIdx.y * 8 + threadIdx.x;

    for (int i = tid; i < TH * TH * TH; i += 512) {
        int lx = i % TH; int r = i / TH; int ly = r % TH; int lz = r / TH;
        int gx = bx + lx - 2, gy = by + ly - 2, gz = bz + lz - 2;
        float vs = 0.f, vt = 0.f;
        if (gx >= 0 && gx < WW && gy >= 0 && gy < HH && gz >= 0 && gz < DD) {
            int gi = (gz * HH + gy) * WW + gx;
            vs = src[gi]; vt = tgt[gi];
        }
        sS[lz][ly][lx] = vs; sT[lz][ly][lx] = vt;
    }
    __syncthreads();

    const int lx = threadIdx.x, ly = threadIdx.y, lz = threadIdx.z;
    float S1 = 0.f, T1 = 0.f, S2 = 0.f, T2 = 0.f, ST = 0.f;
    for (int dz = 0; dz < 5; dz++)
        for (int dy = 0; dy < 5; dy++)
            #pragma unroll
            for (int dx = 0; dx < 5; dx++) {
                float s = sS[lz + dz][ly + dy][lx + dx];
                float t = sT[lz + dz][ly + dy][lx + dx];
                S1 += s; T1 += t;
                S2 = fmaf(s, s, S2);
                T2 = fmaf(t, t, T2);
                ST = fmaf(s, t, ST);
            }
    const float inv125 = 1.f / 125.f;
    float sm = S1 * inv125, tm = T1 * inv125;
    float sv = S2 * inv125 - sm * sm;
    float tv = T2 * inv125 - tm * tm;
    float cross = ST * inv125 - sm * tm;
    float l = cross * cross / (sv * tv + 1e-5f);
    block_atomic_add((double)l, &ws[0], tid, 512);
}

// ---------- 2) grad3d L2 ----------
__global__ __launch_bounds__(256) void grad_kernel(const float* __restrict__ d,
                                                   double* __restrict__ ws) {
    const int idx = blockIdx.x * 256 + threadIdx.x;   // over 3*NN
    double acc = 0.0;
    if (idx < 3 * NN) {
        int r = idx % NN;
        int x = r % WW; int t2 = r / WW; int y = t2 % HH; int z = t2 / HH;
        float v = d[idx];
        float a = 0.f;
        if (z < DD - 1) { float dd = d[idx + HH * WW] - v; a = fmaf(dd, dd, a); }
        if (y < HH - 1) { float dd = d[idx + WW] - v;      a = fmaf(dd, dd, a); }
        if (x < WW - 1) { float dd = d[idx + 1] - v;       a = fmaf(dd, dd, a); }
        acc = (double)a;
    }
    block_atomic_add(acc, &ws[1], threadIdx.x, 256);
}

// ---------- 3) negative Jacobian ----------
__global__ __launch_bounds__(256) void jac_kernel(const float* __restrict__ d,
                                                  double* __restrict__ ws) {
    const int idx = blockIdx.x * 256 + threadIdx.x;   // over 127^3
    double acc = 0.0;
    if (idx < DJ * DJ * DJ) {
        int x = idx % DJ; int r = idx / DJ; int y = r % DJ; int z = r / DJ;
        int base = (z * HH + y) * WW + x;
        float Dz[3], Dy[3], Dx[3];
        #pragma unroll
        for (int c = 0; c < 3; c++) {
            const float* p = d + c * NN + base;
            float v = p[0];
            Dz[c] = p[HH * WW] - v;   // diff along D axis ("dx" in ref)
            Dy[c] = p[WW] - v;        // diff along H axis ("dy" in ref)
            Dx[c] = p[1] - v;         // diff along W axis ("dz" in ref)
        }
        float a00 = 1.f + Dz[0], a01 = Dy[0], a02 = Dx[0];
        float a10 = Dz[1], a11 = 1.f + Dy[1], a12 = Dx[1];
        float a20 = Dz[2], a21 = Dy[2], a22 = 1.f + Dx[2];
        float det = a00 * (a11 * a22 - a12 * a21)
                  - a01 * (a10 * a22 - a12 * a20)
                  + a02 * (a10 * a21 - a11 * a20);
        if (isnan(det)) det = 0.f;
        else if (isinf(det)) det = det > 0.f ? 1000.f : -1000.f;
        float r_ = -det;
        acc = (double)(r_ > 0.f ? r_ : 0.f);
    }
    block_atomic_add(acc, &ws[2], threadIdx.x, 256);
}

// ---------- 4) inverse consistency ----------
__global__ __launch_bounds__(256) void inv_kernel(const float* __restrict__ fwd,
                                                  const float* __restrict__ bwd,
                                                  double* __restrict__ ws) {
    const int idx = blockIdx.x * 256 + threadIdx.x;   // over NN voxels
    double acc = 0.0;
    if (idx < NN) {
        int x = idx % WW; int r = idx / WW; int y = r % HH; int z = r / HH;
        float f0 = fwd[idx], f1 = fwd[NN + idx], f2 = fwd[2 * NN + idx];
        float cz = fminf(fmaxf((float)z + f0, 0.f), (float)(DD - 1));
        float cy = fminf(fmaxf((float)y + f1, 0.f), (float)(HH - 1));
        float cx = fminf(fmaxf((float)x + f2, 0.f), (float)(WW - 1));
        float z0f = floorf(cz), y0f = floorf(cy), x0f = floorf(cx);
        float fz = cz - z0f, fy = cy - y0f, fx = cx - x0f;
        int z0 = (int)z0f, y0 = (int)y0f, x0 = (int)x0f;
        int z1 = min(z0 + 1, DD - 1), y1 = min(y0 + 1, HH - 1), x1 = min(x0 + 1, WW - 1);
        int i000 = (z0 * HH + y0) * WW + x0;
        int i001 = (z0 * HH + y0) * WW + x1;
        int i010 = (z0 * HH + y1) * WW + x0;
        int i011 = (z0 * HH + y1) * WW + x1;
        int i100 = (z1 * HH + y0) * WW + x0;
        int i101 = (z1 * HH + y0) * WW + x1;
        int i110 = (z1 * HH + y1) * WW + x0;
        int i111 = (z1 * HH + y1) * WW + x1;
        float w000 = (1.f - fz) * (1.f - fy) * (1.f - fx);
        float w001 = (1.f - fz) * (1.f - fy) * fx;
        float w010 = (1.f - fz) * fy * (1.f - fx);
        float w011 = (1.f - fz) * fy * fx;
        float w100 = fz * (1.f - fy) * (1.f - fx);
        float w101 = fz * (1.f - fy) * fx;
        float w110 = fz * fy * (1.f - fx);
        float w111 = fz * fy * fx;
        float fc[3] = {f0, f1, f2};
        #pragma unroll
        for (int c = 0; c < 3; c++) {
            const float* b = bwd + c * NN;
            float warped = w000 * b[i000] + w001 * b[i001]
                         + w010 * b[i010] + w011 * b[i011]
                         + w100 * b[i100] + w101 * b[i101]
                         + w110 * b[i110] + w111 * b[i111];
            float comp = fc[c] + warped;
            acc += (double)(comp * comp);
        }
    }
    block_atomic_add(acc, &ws[3], threadIdx.x, 256);
}

// ---------- 5) finalize ----------
__global__ void finalize_kernel(const double* __restrict__ ws, float* __restrict__ out) {
    if (threadIdx.x == 0 && blockIdx.x == 0) {
        double li = 1.0 - ws[0] / (double)NN;
        if (isnan(li) || isinf(li)) li = 1.0;

        double grad = ws[1] / (9.0 * 127.0 * 128.0 * 128.0);

        double jac = ws[2] / ((double)DJ * DJ * DJ);

        double inv = ws[3] / (3.0 * (double)NN);
        if (isnan(inv)) inv = 0.0;
        else if (isinf(inv)) inv = inv > 0.0 ? 1000.0 : 0.0;

        out[0] = (float)(1.0 * li + 0.02 * grad + 0.01 * jac + 0.1 * inv);
    }
}

extern "C" void kernel_launch(void* const* d_in, const int* in_sizes, int n_in,
                              void* d_out, int out_size, void* d_ws, size_t ws_size,
                              hipStream_t stream) {
    const float* src = (const float*)d_in[0];
    const float* tgt = (const float*)d_in[1];
    const float* fwd = (const float*)d_in[2];
    const float* bwd = (const float*)d_in[3];
    double* ws = (double*)d_ws;
    float* out = (float*)d_out;

    hipMemsetAsync(d_ws, 0, 4 * sizeof(double), stream);

    dim3 bl(8, 8, 8), gr(16, 16, 16);
    lncc_kernel<<<gr, bl, 0, stream>>>(src, tgt, ws);
    grad_kernel<<<(3 * NN + 255) / 256, 256, 0, stream>>>(fwd, ws);
    jac_kernel<<<(DJ * DJ * DJ + 255) / 256, 256, 0, stream>>>(fwd, ws);
    inv_kernel<<<(NN + 255) / 256, 256, 0, stream>>>(fwd, bwd, ws);
    finalize_kernel<<<1, 64, 0, stream>>>(ws, out);
}

// Round 2
// 150.510 us; speedup vs baseline: 3.8777x; 3.8777x over previous
//
#include <hip/hip_runtime.h>
#include <math.h>

#define DD 128
#define HH 128
#define WW 128
#define NN (DD*HH*WW)
#define DJ 127

// workspace slot layout (doubles)
#define NB_LNCC 4096
#define NB_FUSED 2048
#define LOFF 0
#define GOFF (NB_LNCC)
#define JOFF (NB_LNCC + NB_FUSED)
#define IOFF (NB_LNCC + 2*NB_FUSED)
#define NSLOTS (NB_LNCC + 3*NB_FUSED)

// ---------- reduction helpers ----------
__device__ __forceinline__ double wave_reduce(double v) {
    #pragma unroll
    for (int o = 32; o > 0; o >>= 1) v += __shfl_down(v, o);
    return v;
}

// Valid result on tid==0 only. All threads must call. Reusable (syncs internally).
template <int NWAVES>
__device__ __forceinline__ double block_reduce(double v, double* red, int tid) {
    v = wave_reduce(v);
    int wid = tid >> 6, lane = tid & 63;
    __syncthreads();               // protect shared reuse across calls
    if (lane == 0) red[wid] = v;
    __syncthreads();
    double x = 0.0;
    if (tid == 0) {
        #pragma unroll
        for (int w = 0; w < NWAVES; w++) x += red[w];
    }
    return x;
}

// ---------- 1) LNCC ----------
#define TB 8
#define TH 12   // TB + 2*2 halo

__global__ __launch_bounds__(512) void lncc_kernel(const float* __restrict__ src,
                                                   const float* __restrict__ tgt,
                                                   double* __restrict__ ws) {
    __shared__ float sS[TH][TH][TH];
    __shared__ float sT[TH][TH][TH];
    __shared__ double red[8];
    const int bx = blockIdx.x * TB, by = blockIdx.y * TB, bz = blockIdx.z * TB;
    const int tid = threadIdx.z * 64 + threadIdx.y * 8 + threadIdx.x;

    for (int i = tid; i < TH * TH * TH; i += 512) {
        int lx = i % TH; int r = i / TH; int ly = r % TH; int lz = r / TH;
        int gx = bx + lx - 2, gy = by + ly - 2, gz = bz + lz - 2;
        float vs = 0.f, vt = 0.f;
        if (gx >= 0 && gx < WW && gy >= 0 && gy < HH && gz >= 0 && gz < DD) {
            int gi = (gz * HH + gy) * WW + gx;
            vs = src[gi]; vt = tgt[gi];
        }
        sS[lz][ly][lx] = vs; sT[lz][ly][lx] = vt;
    }
    __syncthreads();

    const int lx = threadIdx.x, ly = threadIdx.y, lz = threadIdx.z;
    float S1 = 0.f, T1 = 0.f, S2 = 0.f, T2 = 0.f, ST = 0.f;
    for (int dz = 0; dz < 5; dz++)
        for (int dy = 0; dy < 5; dy++)
            #pragma unroll
            for (int dx = 0; dx < 5; dx++) {
                float s = sS[lz + dz][ly + dy][lx + dx];
                float t = sT[lz + dz][ly + dy][lx + dx];
                S1 += s; T1 += t;
                S2 = fmaf(s, s, S2);
                T2 = fmaf(t, t, T2);
                ST = fmaf(s, t, ST);
            }
    const float inv125 = 1.f / 125.f;
    float sm = S1 * inv125, tm = T1 * inv125;
    float sv = S2 * inv125 - sm * sm;
    float tv = T2 * inv125 - tm * tm;
    float cross = ST * inv125 - sm * tm;
    float l = cross * cross / (sv * tv + 1e-5f);

    double tot = block_reduce<8>((double)l, red, tid);
    if (tid == 0) {
        int bid = (blockIdx.z * gridDim.y + blockIdx.y) * gridDim.x + blockIdx.x;
        ws[LOFF + bid] = tot;
    }
}

// ---------- 2) fused grad + jac + inverse-consistency ----------
__global__ __launch_bounds__(256) void fused_kernel(const float* __restrict__ fwd,
                                                    const float* __restrict__ bwd,
                                                    double* __restrict__ ws) {
    __shared__ double red[4];
    double accG = 0.0, accJ = 0.0, accI = 0.0;

    for (int idx = blockIdx.x * 256 + threadIdx.x; idx < NN; idx += gridDim.x * 256) {
        const int x = idx % WW; int r = idx / WW; const int y = r % HH; const int z = r / HH;
        const bool hx = (x < WW - 1), hy = (y < HH - 1), hz = (z < DD - 1);

        float v[3], ddx[3], ddy[3], ddz[3];
        #pragma unroll
        for (int c = 0; c < 3; c++) {
            const float* p = fwd + c * NN + idx;
            float vv = p[0];
            v[c]   = vv;
            ddx[c] = hx ? (p[1] - vv) : 0.f;
            ddy[c] = hy ? (p[WW] - vv) : 0.f;
            ddz[c] = hz ? (p[HH * WW] - vv) : 0.f;
        }

        // --- grad3d L2 (sum of squared forward diffs; invalid ones are 0) ---
        float g = 0.f;
        #pragma unroll
        for (int c = 0; c < 3; c++)
            g = fmaf(ddz[c], ddz[c], fmaf(ddy[c], ddy[c], fmaf(ddx[c], ddx[c], g)));
        accG += (double)g;

        // --- negative Jacobian (interior 127^3; same forward diffs) ---
        if (x < DJ && y < DJ && z < DJ) {
            // ref: dx = diff along D(z axis), dy = along H, dz = along W
            float a00 = 1.f + ddz[0], a01 = ddy[0], a02 = ddx[0];
            float a10 = ddz[1], a11 = 1.f + ddy[1], a12 = ddx[1];
            float a20 = ddz[2], a21 = ddy[2], a22 = 1.f + ddx[2];
            float det = a00 * (a11 * a22 - a12 * a21)
                      - a01 * (a10 * a22 - a12 * a20)
                      + a02 * (a10 * a21 - a11 * a20);
            if (isnan(det)) det = 0.f;
            else if (isinf(det)) det = det > 0.f ? 1000.f : -1000.f;
            float neg = -det;
            if (neg > 0.f) accJ += (double)neg;
        }

        // --- inverse consistency: fwd + warp(bwd, fwd), trilinear ---
        {
            float cz = fminf(fmaxf((float)z + v[0], 0.f), (float)(DD - 1));
            float cy = fminf(fmaxf((float)y + v[1], 0.f), (float)(HH - 1));
            float cx = fminf(fmaxf((float)x + v[2], 0.f), (float)(WW - 1));
            float z0f = floorf(cz), y0f = floorf(cy), x0f = floorf(cx);
            float fz = cz - z0f, fy = cy - y0f, fx = cx - x0f;
            int z0 = (int)z0f, y0 = (int)y0f, x0 = (int)x0f;
            int z1 = min(z0 + 1, DD - 1), y1 = min(y0 + 1, HH - 1), x1 = min(x0 + 1, WW - 1);
            int i000 = (z0 * HH + y0) * WW + x0;
            int i001 = (z0 * HH + y0) * WW + x1;
            int i010 = (z0 * HH + y1) * WW + x0;
            int i011 = (z0 * HH + y1) * WW + x1;
            int i100 = (z1 * HH + y0) * WW + x0;
            int i101 = (z1 * HH + y0) * WW + x1;
            int i110 = (z1 * HH + y1) * WW + x0;
            int i111 = (z1 * HH + y1) * WW + x1;
            float w000 = (1.f - fz) * (1.f - fy) * (1.f - fx);
            float w001 = (1.f - fz) * (1.f - fy) * fx;
            float w010 = (1.f - fz) * fy * (1.f - fx);
            float w011 = (1.f - fz) * fy * fx;
            float w100 = fz * (1.f - fy) * (1.f - fx);
            float w101 = fz * (1.f - fy) * fx;
            float w110 = fz * fy * (1.f - fx);
            float w111 = fz * fy * fx;
            #pragma unroll
            for (int c = 0; c < 3; c++) {
                const float* b = bwd + c * NN;
                float warped = w000 * b[i000] + w001 * b[i001]
                             + w010 * b[i010] + w011 * b[i011]
                             + w100 * b[i100] + w101 * b[i101]
                             + w110 * b[i110] + w111 * b[i111];
                float comp = v[c] + warped;
                accI += (double)(comp * comp);
            }
        }
    }

    double tG = block_reduce<4>(accG, red, threadIdx.x);
    double tJ = block_reduce<4>(accJ, red, threadIdx.x);
    double tI = block_reduce<4>(accI, red, threadIdx.x);
    if (threadIdx.x == 0) {
        ws[GOFF + blockIdx.x] = tG;
        ws[JOFF + blockIdx.x] = tJ;
        ws[IOFF + blockIdx.x] = tI;
    }
}

// ---------- 3) finalize: sum slots, weights, nan_to_num ----------
__global__ __launch_bounds__(256) void finalize_kernel(const double* __restrict__ ws,
                                                       float* __restrict__ out) {
    __shared__ double red[4];
    double l = 0.0, g = 0.0, j = 0.0, inv = 0.0;
    for (int k = threadIdx.x; k < NB_LNCC; k += 256) l += ws[LOFF + k];
    for (int k = threadIdx.x; k < NB_FUSED; k += 256) {
        g   += ws[GOFF + k];
        j   += ws[JOFF + k];
        inv += ws[IOFF + k];
    }
    double tl = block_reduce<4>(l, red, threadIdx.x);
    double tg = block_reduce<4>(g, red, threadIdx.x);
    double tj = block_reduce<4>(j, red, threadIdx.x);
    double ti = block_reduce<4>(inv, red, threadIdx.x);
    if (threadIdx.x == 0) {
        double li = 1.0 - tl / (double)NN;
        if (isnan(li) || isinf(li)) li = 1.0;

        double grad = tg / (9.0 * 127.0 * 128.0 * 128.0);
        double jac  = tj / ((double)DJ * DJ * DJ);

        double iv = ti / (3.0 * (double)NN);
        if (isnan(iv)) iv = 0.0;
        else if (isinf(iv)) iv = iv > 0.0 ? 1000.0 : 0.0;

        out[0] = (float)(1.0 * li + 0.02 * grad + 0.01 * jac + 0.1 * iv);
    }
}

extern "C" void kernel_launch(void* const* d_in, const int* in_sizes, int n_in,
                              void* d_out, int out_size, void* d_ws, size_t ws_size,
                              hipStream_t stream) {
    const float* src = (const float*)d_in[0];
    const float* tgt = (const float*)d_in[1];
    const float* fwd = (const float*)d_in[2];
    const float* bwd = (const float*)d_in[3];
    double* ws = (double*)d_ws;
    float* out = (float*)d_out;

    // Every slot consumed by finalize_kernel is unconditionally written by its
    // producer block, so no workspace memset is needed.
    dim3 bl(8, 8, 8), gr(16, 16, 16);
    lncc_kernel<<<gr, bl, 0, stream>>>(src, tgt, ws);
    fused_kernel<<<NB_FUSED, 256, 0, stream>>>(fwd, bwd, ws);
    finalize_kernel<<<1, 256, 0, stream>>>(ws, out);
}

// Round 3
// 97.342 us; speedup vs baseline: 5.9957x; 1.5462x over previous
//
#include <hip/hip_runtime.h>
#include <math.h>

#define DD 128
#define HH 128
#define WW 128
#define NN (DD*HH*WW)
#define DJ 127

// workspace layout: [slots: doubles][bwd interleaved float4 volume]
#define NB_LNCC 4096
#define NB_FUSED 2048
#define LOFF 0
#define GOFF (NB_LNCC)
#define JOFF (NB_LNCC + NB_FUSED)
#define IOFF (NB_LNCC + 2*NB_FUSED)
#define NSLOTS (NB_LNCC + 3*NB_FUSED)
#define BWDI_OFF ((size_t)NSLOTS * 8)            // 81920 B, 16B aligned
#define WS_NEED (BWDI_OFF + (size_t)NN * 16)

// ---------- reduction helpers ----------
__device__ __forceinline__ double wave_reduce(double v) {
    #pragma unroll
    for (int o = 32; o > 0; o >>= 1) v += __shfl_down(v, o);
    return v;
}

template <int NWAVES>
__device__ __forceinline__ double block_reduce(double v, double* red, int tid) {
    v = wave_reduce(v);
    int wid = tid >> 6, lane = tid & 63;
    __syncthreads();
    if (lane == 0) red[wid] = v;
    __syncthreads();
    double x = 0.0;
    if (tid == 0) {
        #pragma unroll
        for (int w = 0; w < NWAVES; w++) x += red[w];
    }
    return x;
}

// ---------- 0) channel-interleave bwd into float4 volume ----------
__global__ __launch_bounds__(256) void interleave_kernel(const float* __restrict__ bwd,
                                                         float4* __restrict__ bwdi) {
    int i = blockIdx.x * 256 + threadIdx.x;
    bwdi[i] = make_float4(bwd[i], bwd[NN + i], bwd[2 * NN + i], 0.f);
}

// ---------- 1) LNCC, separable 5x5x5 box filter in LDS ----------
#define TB 8
#define TH 12   // TB + 2*2 halo

__global__ __launch_bounds__(512) void lncc_kernel(const float* __restrict__ src,
                                                   const float* __restrict__ tgt,
                                                   double* __restrict__ ws) {
    __shared__ float sS[TH * TH * TH];
    __shared__ float sT[TH * TH * TH];
    __shared__ float F1[5][TH * TH * TB];   // after x-pass  [field][(lz*12+ly)*8+ox]
    __shared__ float F2[5][TH * TB * TB];   // after y-pass  [field][(lz*8+oy)*8+ox]
    __shared__ double red[8];
    const int bx = blockIdx.x * TB, by = blockIdx.y * TB, bz = blockIdx.z * TB;
    const int tid = threadIdx.z * 64 + threadIdx.y * 8 + threadIdx.x;

    // stage 12^3 tiles (zero-padded outside the volume, matching reduce_window)
    for (int i = tid; i < TH * TH * TH; i += 512) {
        int lx = i % TH; int r = i / TH; int ly = r % TH; int lz = r / TH;
        int gx = bx + lx - 2, gy = by + ly - 2, gz = bz + lz - 2;
        float vs = 0.f, vt = 0.f;
        if (gx >= 0 && gx < WW && gy >= 0 && gy < HH && gz >= 0 && gz < DD) {
            int gi = (gz * HH + gy) * WW + gx;
            vs = src[gi]; vt = tgt[gi];
        }
        sS[i] = vs; sT[i] = vt;
    }
    __syncthreads();

    // x-pass: 5-moment window sums along x; outputs 12*12*8
    for (int i = tid; i < TH * TH * TB; i += 512) {
        int ox = i & 7; int r = i >> 3; int ly = r % TH; int lz = r / TH;
        int base = (lz * TH + ly) * TH + ox;
        float s1 = 0.f, t1 = 0.f, s2 = 0.f, t2 = 0.f, st = 0.f;
        #pragma unroll
        for (int dx = 0; dx < 5; dx++) {
            float s = sS[base + dx], t = sT[base + dx];
            s1 += s; t1 += t;
            s2 = fmaf(s, s, s2); t2 = fmaf(t, t, t2); st = fmaf(s, t, st);
        }
        F1[0][i] = s1; F1[1][i] = t1; F1[2][i] = s2; F1[3][i] = t2; F1[4][i] = st;
    }
    __syncthreads();

    // y-pass: outputs 12*8*8
    for (int i = tid; i < TH * TB * TB; i += 512) {
        int ox = i & 7; int r = i >> 3; int oy = r & 7; int lz = r >> 3;
        float a0 = 0.f, a1 = 0.f, a2 = 0.f, a3 = 0.f, a4 = 0.f;
        #pragma unroll
        for (int dy = 0; dy < 5; dy++) {
            int j = (lz * TH + oy + dy) * TB + ox;
            a0 += F1[0][j]; a1 += F1[1][j]; a2 += F1[2][j]; a3 += F1[3][j]; a4 += F1[4][j];
        }
        F2[0][i] = a0; F2[1][i] = a1; F2[2][i] = a2; F2[3][i] = a3; F2[4][i] = a4;
    }
    __syncthreads();

    // z-pass + lncc: one output voxel per thread (8^3 = 512)
    {
        int ox = tid & 7; int r = tid >> 3; int oy = r & 7; int oz = r >> 3;
        float S1 = 0.f, T1 = 0.f, S2 = 0.f, T2 = 0.f, ST = 0.f;
        #pragma unroll
        for (int dz = 0; dz < 5; dz++) {
            int j = ((oz + dz) * TB + oy) * TB + ox;
            S1 += F2[0][j]; T1 += F2[1][j]; S2 += F2[2][j]; T2 += F2[3][j]; ST += F2[4][j];
        }
        const float inv125 = 1.f / 125.f;
        float sm = S1 * inv125, tm = T1 * inv125;
        float sv = S2 * inv125 - sm * sm;
        float tv = T2 * inv125 - tm * tm;
        float cross = ST * inv125 - sm * tm;
        float l = cross * cross / (sv * tv + 1e-5f);

        double tot = block_reduce<8>((double)l, red, tid);
        if (tid == 0) {
            int bid = (blockIdx.z * gridDim.y + blockIdx.y) * gridDim.x + blockIdx.x;
            ws[LOFF + bid] = tot;
        }
    }
}

// ---------- 2) fused grad + jac + inverse-consistency, 4 voxels/thread ----------
__global__ __launch_bounds__(256) void fused4_kernel(const float* __restrict__ fwd,
                                                     const float4* __restrict__ bwdi,
                                                     double* __restrict__ ws) {
    __shared__ double red[4];
    double accG = 0.0, accJ = 0.0, accI = 0.0;

    const int t4 = (blockIdx.x * 256 + threadIdx.x) * 4;   // base voxel (x % 4 == 0)
    const int x = t4 & 127; int rr = t4 >> 7; const int y = rr & 127; const int z = rr >> 7;
    const bool hy = (y < HH - 1), hz = (z < DD - 1);

    // per-channel: 5 x-values (float4 + next scalar), y+1 row, z+1 slice
    float av[3][5]; float4 Y4[3], Z4[3];
    #pragma unroll
    for (int c = 0; c < 3; c++) {
        const float* p = fwd + c * NN + t4;
        float4 q = *(const float4*)p;
        av[c][0] = q.x; av[c][1] = q.y; av[c][2] = q.z; av[c][3] = q.w;
        av[c][4] = (x < 124) ? p[4] : 0.f;
        Y4[c] = hy ? *(const float4*)(p + WW) : make_float4(0.f, 0.f, 0.f, 0.f);
        Z4[c] = hz ? *(const float4*)(p + WW * HH) : make_float4(0.f, 0.f, 0.f, 0.f);
    }

    #pragma unroll
    for (int j = 0; j < 4; j++) {
        const int xj = x + j;
        const bool hx = (xj < WW - 1);
        float v[3], ddx[3], ddy[3], ddz[3];
        #pragma unroll
        for (int c = 0; c < 3; c++) {
            float vv = av[c][j];
            float yv = (c == 0 ? (j == 0 ? Y4[0].x : j == 1 ? Y4[0].y : j == 2 ? Y4[0].z : Y4[0].w)
                      : c == 1 ? (j == 0 ? Y4[1].x : j == 1 ? Y4[1].y : j == 2 ? Y4[1].z : Y4[1].w)
                               : (j == 0 ? Y4[2].x : j == 1 ? Y4[2].y : j == 2 ? Y4[2].z : Y4[2].w));
            float zv = (c == 0 ? (j == 0 ? Z4[0].x : j == 1 ? Z4[0].y : j == 2 ? Z4[0].z : Z4[0].w)
                      : c == 1 ? (j == 0 ? Z4[1].x : j == 1 ? Z4[1].y : j == 2 ? Z4[1].z : Z4[1].w)
                               : (j == 0 ? Z4[2].x : j == 1 ? Z4[2].y : j == 2 ? Z4[2].z : Z4[2].w));
            v[c]   = vv;
            ddx[c] = hx ? (av[c][j + 1] - vv) : 0.f;
            ddy[c] = hy ? (yv - vv) : 0.f;
            ddz[c] = hz ? (zv - vv) : 0.f;
        }

        // grad3d L2
        float g = 0.f;
        #pragma unroll
        for (int c = 0; c < 3; c++)
            g = fmaf(ddz[c], ddz[c], fmaf(ddy[c], ddy[c], fmaf(ddx[c], ddx[c], g)));
        accG += (double)g;

        // negative Jacobian (interior only)
        if (hx && hy && hz) {
            float a00 = 1.f + ddz[0], a01 = ddy[0], a02 = ddx[0];
            float a10 = ddz[1], a11 = 1.f + ddy[1], a12 = ddx[1];
            float a20 = ddz[2], a21 = ddy[2], a22 = 1.f + ddx[2];
            float det = a00 * (a11 * a22 - a12 * a21)
                      - a01 * (a10 * a22 - a12 * a20)
                      + a02 * (a10 * a21 - a11 * a20);
            if (isnan(det)) det = 0.f;
            else if (isinf(det)) det = det > 0.f ? 1000.f : -1000.f;
            float neg = -det;
            if (neg > 0.f) accJ += (double)neg;
        }

        // inverse consistency via interleaved gather (8 x float4)
        {
            float cz = fminf(fmaxf((float)z + v[0], 0.f), (float)(DD - 1));
            float cy = fminf(fmaxf((float)y + v[1], 0.f), (float)(HH - 1));
            float cx = fminf(fmaxf((float)xj + v[2], 0.f), (float)(WW - 1));
            float z0f = floorf(cz), y0f = floorf(cy), x0f = floorf(cx);
            float fz = cz - z0f, fy = cy - y0f, fx = cx - x0f;
            int z0 = (int)z0f, y0 = (int)y0f, x0 = (int)x0f;
            int z1 = min(z0 + 1, DD - 1), y1 = min(y0 + 1, HH - 1), x1 = min(x0 + 1, WW - 1);
            int b00 = (z0 * HH + y0) * WW, b01 = (z0 * HH + y1) * WW;
            int b10 = (z1 * HH + y0) * WW, b11 = (z1 * HH + y1) * WW;
            float4 C000 = bwdi[b00 + x0], C001 = bwdi[b00 + x1];
            float4 C010 = bwdi[b01 + x0], C011 = bwdi[b01 + x1];
            float4 C100 = bwdi[b10 + x0], C101 = bwdi[b10 + x1];
            float4 C110 = bwdi[b11 + x0], C111 = bwdi[b11 + x1];
            float w000 = (1.f - fz) * (1.f - fy) * (1.f - fx);
            float w001 = (1.f - fz) * (1.f - fy) * fx;
            float w010 = (1.f - fz) * fy * (1.f - fx);
            float w011 = (1.f - fz) * fy * fx;
            float w100 = fz * (1.f - fy) * (1.f - fx);
            float w101 = fz * (1.f - fy) * fx;
            float w110 = fz * fy * (1.f - fx);
            float w111 = fz * fy * fx;
            float c0 = v[0] + w000 * C000.x + w001 * C001.x + w010 * C010.x + w011 * C011.x
                            + w100 * C100.x + w101 * C101.x + w110 * C110.x + w111 * C111.x;
            float c1 = v[1] + w000 * C000.y + w001 * C001.y + w010 * C010.y + w011 * C011.y
                            + w100 * C100.y + w101 * C101.y + w110 * C110.y + w111 * C111.y;
            float c2 = v[2] + w000 * C000.z + w001 * C001.z + w010 * C010.z + w011 * C011.z
                            + w100 * C100.z + w101 * C101.z + w110 * C110.z + w111 * C111.z;
            accI += (double)(c0 * c0 + c1 * c1 + c2 * c2);
        }
    }

    double tG = block_reduce<4>(accG, red, threadIdx.x);
    double tJ = block_reduce<4>(accJ, red, threadIdx.x);
    double tI = block_reduce<4>(accI, red, threadIdx.x);
    if (threadIdx.x == 0) {
        ws[GOFF + blockIdx.x] = tG;
        ws[JOFF + blockIdx.x] = tJ;
        ws[IOFF + blockIdx.x] = tI;
    }
}

// ---------- 2b) fallback fused kernel (scalar gathers; used if ws too small) ----------
__global__ __launch_bounds__(256) void fused_kernel(const float* __restrict__ fwd,
                                                    const float* __restrict__ bwd,
                                                    double* __restrict__ ws) {
    __shared__ double red[4];
    double accG = 0.0, accJ = 0.0, accI = 0.0;

    for (int idx = blockIdx.x * 256 + threadIdx.x; idx < NN; idx += gridDim.x * 256) {
        const int x = idx % WW; int r = idx / WW; const int y = r % HH; const int z = r / HH;
        const bool hx = (x < WW - 1), hy = (y < HH - 1), hz = (z < DD - 1);

        float v[3], ddx[3], ddy[3], ddz[3];
        #pragma unroll
        for (int c = 0; c < 3; c++) {
            const float* p = fwd + c * NN + idx;
            float vv = p[0];
            v[c]   = vv;
            ddx[c] = hx ? (p[1] - vv) : 0.f;
            ddy[c] = hy ? (p[WW] - vv) : 0.f;
            ddz[c] = hz ? (p[HH * WW] - vv) : 0.f;
        }
        float g = 0.f;
        #pragma unroll
        for (int c = 0; c < 3; c++)
            g = fmaf(ddz[c], ddz[c], fmaf(ddy[c], ddy[c], fmaf(ddx[c], ddx[c], g)));
        accG += (double)g;

        if (x < DJ && y < DJ && z < DJ) {
            float a00 = 1.f + ddz[0], a01 = ddy[0], a02 = ddx[0];
            float a10 = ddz[1], a11 = 1.f + ddy[1], a12 = ddx[1];
            float a20 = ddz[2], a21 = ddy[2], a22 = 1.f + ddx[2];
            float det = a00 * (a11 * a22 - a12 * a21)
                      - a01 * (a10 * a22 - a12 * a20)
                      + a02 * (a10 * a21 - a11 * a20);
            if (isnan(det)) det = 0.f;
            else if (isinf(det)) det = det > 0.f ? 1000.f : -1000.f;
            float neg = -det;
            if (neg > 0.f) accJ += (double)neg;
        }
        {
            float cz = fminf(fmaxf((float)z + v[0], 0.f), (float)(DD - 1));
            float cy = fminf(fmaxf((float)y + v[1], 0.f), (float)(HH - 1));
            float cx = fminf(fmaxf((float)x + v[2], 0.f), (float)(WW - 1));
            float z0f = floorf(cz), y0f = floorf(cy), x0f = floorf(cx);
            float fz = cz - z0f, fy = cy - y0f, fx = cx - x0f;
            int z0 = (int)z0f, y0 = (int)y0f, x0 = (int)x0f;
            int z1 = min(z0 + 1, DD - 1), y1 = min(y0 + 1, HH - 1), x1 = min(x0 + 1, WW - 1);
            int i000 = (z0 * HH + y0) * WW + x0, i001 = (z0 * HH + y0) * WW + x1;
            int i010 = (z0 * HH + y1) * WW + x0, i011 = (z0 * HH + y1) * WW + x1;
            int i100 = (z1 * HH + y0) * WW + x0, i101 = (z1 * HH + y0) * WW + x1;
            int i110 = (z1 * HH + y1) * WW + x0, i111 = (z1 * HH + y1) * WW + x1;
            float w000 = (1.f - fz) * (1.f - fy) * (1.f - fx);
            float w001 = (1.f - fz) * (1.f - fy) * fx;
            float w010 = (1.f - fz) * fy * (1.f - fx);
            float w011 = (1.f - fz) * fy * fx;
            float w100 = fz * (1.f - fy) * (1.f - fx);
            float w101 = fz * (1.f - fy) * fx;
            float w110 = fz * fy * (1.f - fx);
            float w111 = fz * fy * fx;
            #pragma unroll
            for (int c = 0; c < 3; c++) {
                const float* b = bwd + c * NN;
                float warped = w000 * b[i000] + w001 * b[i001]
                             + w010 * b[i010] + w011 * b[i011]
                             + w100 * b[i100] + w101 * b[i101]
                             + w110 * b[i110] + w111 * b[i111];
                float comp = v[c] + warped;
                accI += (double)(comp * comp);
            }
        }
    }

    double tG = block_reduce<4>(accG, red, threadIdx.x);
    double tJ = block_reduce<4>(accJ, red, threadIdx.x);
    double tI = block_reduce<4>(accI, red, threadIdx.x);
    if (threadIdx.x == 0) {
        ws[GOFF + blockIdx.x] = tG;
        ws[JOFF + blockIdx.x] = tJ;
        ws[IOFF + blockIdx.x] = tI;
    }
}

// ---------- 3) finalize ----------
__global__ __launch_bounds__(256) void finalize_kernel(const double* __restrict__ ws,
                                                       float* __restrict__ out) {
    __shared__ double red[4];
    double l = 0.0, g = 0.0, j = 0.0, inv = 0.0;
    for (int k = threadIdx.x; k < NB_LNCC; k += 256) l += ws[LOFF + k];
    for (int k = threadIdx.x; k < NB_FUSED; k += 256) {
        g   += ws[GOFF + k];
        j   += ws[JOFF + k];
        inv += ws[IOFF + k];
    }
    double tl = block_reduce<4>(l, red, threadIdx.x);
    double tg = block_reduce<4>(g, red, threadIdx.x);
    double tj = block_reduce<4>(j, red, threadIdx.x);
    double ti = block_reduce<4>(inv, red, threadIdx.x);
    if (threadIdx.x == 0) {
        double li = 1.0 - tl / (double)NN;
        if (isnan(li) || isinf(li)) li = 1.0;
        double grad = tg / (9.0 * 127.0 * 128.0 * 128.0);
        double jac  = tj / ((double)DJ * DJ * DJ);
        double iv = ti / (3.0 * (double)NN);
        if (isnan(iv)) iv = 0.0;
        else if (isinf(iv)) iv = iv > 0.0 ? 1000.0 : 0.0;
        out[0] = (float)(1.0 * li + 0.02 * grad + 0.01 * jac + 0.1 * iv);
    }
}

extern "C" void kernel_launch(void* const* d_in, const int* in_sizes, int n_in,
                              void* d_out, int out_size, void* d_ws, size_t ws_size,
                              hipStream_t stream) {
    const float* src = (const float*)d_in[0];
    const float* tgt = (const float*)d_in[1];
    const float* fwd = (const float*)d_in[2];
    const float* bwd = (const float*)d_in[3];
    double* ws = (double*)d_ws;
    float* out = (float*)d_out;

    dim3 bl(8, 8, 8), gr(16, 16, 16);
    if (ws_size >= WS_NEED) {
        float4* bwdi = (float4*)((char*)d_ws + BWDI_OFF);
        interleave_kernel<<<NN / 256, 256, 0, stream>>>(bwd, bwdi);
        lncc_kernel<<<gr, bl, 0, stream>>>(src, tgt, ws);
        fused4_kernel<<<NB_FUSED, 256, 0, stream>>>(fwd, bwdi, ws);
    } else {
        lncc_kernel<<<gr, bl, 0, stream>>>(src, tgt, ws);
        fused_kernel<<<NB_FUSED, 256, 0, stream>>>(fwd, bwd, ws);
    }
    finalize_kernel<<<1, 256, 0, stream>>>(ws, out);
}